// Round 5
// baseline (155.639 us; speedup 1.0000x reference)
//
#include <hip/hip_runtime.h>
#include <math.h>

#define D_MODEL 512
#define NHEADS  8
#define NSEQ    2048
#define NBLK    16
#define NCHUNK  72          // sum over m of (m/2+1)
#define EPSF    1e-6f
#define WPLANE  262144      // 512*512 elements per weight plane

typedef short v8s __attribute__((ext_vector_type(8)));
typedef float v4f __attribute__((ext_vector_type(4)));

static __device__ __forceinline__ v4f mfma16(v8s a, v8s b, v4f c) {
  return __builtin_amdgcn_mfma_f32_16x16x32_bf16(a, b, c, 0, 0, 0);
}
static __device__ __forceinline__ ushort bf16rne(float f) {
  uint32_t u = __float_as_uint(f);
  return (ushort)((u + 0x7fffu + ((u >> 16) & 1u)) >> 16);
}
static __device__ __forceinline__ float bf16f(ushort h) {
  return __uint_as_float(((uint32_t)h) << 16);
}

// ---------------------------------------------------------------------------
// W[k][n] fp32 -> Wt[n][k] bf16 planes; hi+lo for z<2 (Wq,Wk), hi-only z>=2.
__global__ __launch_bounds__(256) void prep_w(const float* __restrict__ W0,
                                              const float* __restrict__ W1,
                                              const float* __restrict__ W2,
                                              const float* __restrict__ W3,
                                              ushort* __restrict__ Wth,
                                              ushort* __restrict__ Wtl) {
  __shared__ float T[64][68];
  const int z = blockIdx.z;
  const float* W = (z == 0) ? W0 : (z == 1) ? W1 : (z == 2) ? W2 : W3;
  const int kb = blockIdx.x * 64;
  const int nb = blockIdx.y * 64;
  const int tid = threadIdx.x;
#pragma unroll
  for (int l = 0; l < 4; ++l) {
    int f = tid + l * 256;           // 64 rows(k) x 16 float4(n)
    int row = f >> 4, c4 = f & 15;
    float4 v = *reinterpret_cast<const float4*>(&W[(size_t)(kb + row) * D_MODEL + nb + c4 * 4]);
    T[c4 * 4 + 0][row] = v.x; T[c4 * 4 + 1][row] = v.y;
    T[c4 * 4 + 2][row] = v.z; T[c4 * 4 + 3][row] = v.w;
  }
  __syncthreads();
  ushort* oh = Wth + (size_t)z * WPLANE;
  ushort* ol = Wtl + (size_t)z * WPLANE;   // valid only z<2
#pragma unroll
  for (int l = 0; l < 4; ++l) {
    int f = tid + l * 256;           // 64 rows(n) x 16 groups of 4(k)
    int n_ = f >> 4, k4 = f & 15;
    ushort4 h4, l4;
    float v0 = T[n_][k4 * 4 + 0], v1 = T[n_][k4 * 4 + 1];
    float v2 = T[n_][k4 * 4 + 2], v3 = T[n_][k4 * 4 + 3];
    h4.x = bf16rne(v0); h4.y = bf16rne(v1); h4.z = bf16rne(v2); h4.w = bf16rne(v3);
    *reinterpret_cast<ushort4*>(&oh[(size_t)(nb + n_) * D_MODEL + kb + k4 * 4]) = h4;
    if (z < 2) {
      l4.x = bf16rne(v0 - bf16f(h4.x)); l4.y = bf16rne(v1 - bf16f(h4.y));
      l4.z = bf16rne(v2 - bf16f(h4.z)); l4.w = bf16rne(v3 - bf16f(h4.w));
      *reinterpret_cast<ushort4*>(&ol[(size_t)(nb + n_) * D_MODEL + kb + k4 * 4]) = l4;
    }
  }
}

// ---------------------------------------------------------------------------
// Q/K: 3-term hi/lo MFMA -> hi+lo planes + FUSED row norms (fp32, pre-round).
// V: 1-term bf16 -> Vb plane.
__global__ __launch_bounds__(256) void qkv_gemm(
    const float* __restrict__ x, const ushort* __restrict__ Wth,
    const ushort* __restrict__ Wtl,
    const float* __restrict__ bq, const float* __restrict__ bk,
    const float* __restrict__ bv,
    ushort* __restrict__ Qh_, ushort* __restrict__ Ql_,
    ushort* __restrict__ Kh_, ushort* __restrict__ Kl_,
    ushort* __restrict__ Vb_,
    float* __restrict__ Qn_, float* __restrict__ Kn_) {
  __shared__ ushort Ah[128][40], Al[128][40], Bh[128][40], Bl[128][40];
  const int z = blockIdx.z;
  const bool hl = (z < 2);
  const ushort* Bth = Wth + (size_t)z * WPLANE;
  const ushort* Btl = Wtl + (size_t)z * WPLANE;
  const float* bias = (z == 0) ? bq : (z == 1) ? bk : bv;
  ushort* outH = (z == 0) ? Qh_ : (z == 1) ? Kh_ : Vb_;
  ushort* outL = (z == 0) ? Ql_ : Kl_;

  const int bx = blockIdx.x, by = blockIdx.y;
  const int tid = threadIdx.x;
  const int wid = tid >> 6, lane = tid & 63;
  const int wr = wid >> 1, wc = wid & 1;
  const int g = lane >> 4, lx = lane & 15;

  v4f acc[4][4];
#pragma unroll
  for (int i = 0; i < 4; ++i)
#pragma unroll
    for (int j = 0; j < 4; ++j) acc[i][j] = v4f{0.f, 0.f, 0.f, 0.f};

  for (int k0 = 0; k0 < 16; ++k0) {
    __syncthreads();
#pragma unroll
    for (int l = 0; l < 4; ++l) {
      int f = tid + l * 256;          // 128 rows x 8 float4 (32 k)
      int row = f >> 3, c4 = f & 7;
      float4 a = *reinterpret_cast<const float4*>(&x[(size_t)(by * 128 + row) * D_MODEL + k0 * 32 + c4 * 4]);
      float av[4] = {a.x, a.y, a.z, a.w};
#pragma unroll
      for (int j = 0; j < 4; ++j) {
        ushort hi = bf16rne(av[j]);
        Ah[row][c4 * 4 + j] = hi;
        if (hl) Al[row][c4 * 4 + j] = bf16rne(av[j] - bf16f(hi));
      }
    }
#pragma unroll
    for (int l = 0; l < 2; ++l) {
      int f = tid + l * 256;          // 128 rows x 4 chunks of 8
      int row = f >> 2, c8 = f & 3;
      *reinterpret_cast<uint4*>(&Bh[row][c8 * 8]) =
          *reinterpret_cast<const uint4*>(&Bth[(size_t)(bx * 128 + row) * D_MODEL + k0 * 32 + c8 * 8]);
      if (hl)
        *reinterpret_cast<uint4*>(&Bl[row][c8 * 8]) =
            *reinterpret_cast<const uint4*>(&Btl[(size_t)(bx * 128 + row) * D_MODEL + k0 * 32 + c8 * 8]);
    }
    __syncthreads();
    v8s ah[4], al[4], bh[4], bl[4];
#pragma unroll
    for (int i = 0; i < 4; ++i) {
      ah[i] = *reinterpret_cast<const v8s*>(&Ah[wr * 64 + i * 16 + lx][g * 8]);
      bh[i] = *reinterpret_cast<const v8s*>(&Bh[wc * 64 + i * 16 + lx][g * 8]);
      if (hl) {
        al[i] = *reinterpret_cast<const v8s*>(&Al[wr * 64 + i * 16 + lx][g * 8]);
        bl[i] = *reinterpret_cast<const v8s*>(&Bl[wc * 64 + i * 16 + lx][g * 8]);
      }
    }
#pragma unroll
    for (int i = 0; i < 4; ++i)
#pragma unroll
      for (int j = 0; j < 4; ++j) {
        acc[i][j] = mfma16(ah[i], bh[j], acc[i][j]);
        if (hl) {
          acc[i][j] = mfma16(ah[i], bl[j], acc[i][j]);
          acc[i][j] = mfma16(al[i], bh[j], acc[i][j]);
        }
      }
  }

  float np[4][4];
#pragma unroll
  for (int i = 0; i < 4; ++i)
#pragma unroll
    for (int r = 0; r < 4; ++r) np[i][r] = 0.f;

#pragma unroll
  for (int j = 0; j < 4; ++j) {
    const int col = bx * 128 + wc * 64 + j * 16 + lx;
    const float bj = bias[col];
#pragma unroll
    for (int i = 0; i < 4; ++i)
#pragma unroll
      for (int r = 0; r < 4; ++r) {
        const int row = by * 128 + wr * 64 + i * 16 + g * 4 + r;
        float v = acc[i][j][r] + bj;
        np[i][r] = fmaf(v, v, np[i][r]);
        ushort hi = bf16rne(v);
        outH[(size_t)row * D_MODEL + col] = hi;
        if (hl) outL[(size_t)row * D_MODEL + col] = bf16rne(v - bf16f(hi));
      }
  }
  if (hl) {
    float* Nout = (z == 0) ? Qn_ : Kn_;
    const int hh = bx * 2 + wc;          // head of this wave's 64 cols
#pragma unroll
    for (int i = 0; i < 4; ++i)
#pragma unroll
      for (int r = 0; r < 4; ++r) {
        float s = np[i][r];
        s += __shfl_xor(s, 1, 64);
        s += __shfl_xor(s, 2, 64);
        s += __shfl_xor(s, 4, 64);
        s += __shfl_xor(s, 8, 64);
        if (lx == 0)
          Nout[hh * NSEQ + by * 128 + wr * 64 + i * 16 + g * 4 + r] = s;
      }
  }
}

// ---------------------------------------------------------------------------
// Vb [n][512] bf16 -> Vtb [h][64][2048] (d-major per head)
__global__ __launch_bounds__(256) void vt_prep(const ushort* __restrict__ Vb,
                                               ushort* __restrict__ Vtb) {
  __shared__ ushort T[64][72];
  const int nb = blockIdx.x * 64;
  const int h  = blockIdx.y;
  const int tid = threadIdx.x;
#pragma unroll
  for (int l = 0; l < 2; ++l) {
    int f = tid + l * 256;            // 64 rows(n) x 8 chunks of 8(d)
    int row = f >> 3, c8 = f & 7;
    uint4 w = *reinterpret_cast<const uint4*>(&Vb[(size_t)(nb + row) * D_MODEL + h * 64 + c8 * 8]);
    const ushort* p = reinterpret_cast<const ushort*>(&w);
#pragma unroll
    for (int j = 0; j < 8; ++j) T[c8 * 8 + j][row] = p[j];
  }
  __syncthreads();
#pragma unroll
  for (int l = 0; l < 2; ++l) {
    int f = tid + l * 256;            // 64 rows(d) x 8 chunks of 8(n)
    int d = f >> 3, n8 = f & 7;
    *reinterpret_cast<uint4*>(&Vtb[(size_t)(h * 64 + d) * NSEQ + nb + n8 * 8]) =
        *reinterpret_cast<const uint4*>(&T[d][n8 * 8]);
  }
}

// ---------------------------------------------------------------------------
// Barrier-free attention. grid (144, 8): x -> XCD-remap -> (chunk, z-half);
// 256 threads = 4 independent wave-tasks (16 q-rows each).
// Swapped MFMA: A = K rows (direct from global/L2), B = Q rows (registers)
// -> lane holds S^T: 4 k-rows (regs) x 1 q-col (lane&15). All softmax
// reductions are in-register + 2 shuffles; E goes through a wave-private
// LDS slice (b64 writes / b128 reads). No __syncthreads anywhere.
__global__ __launch_bounds__(256, 5) void attn(
    const ushort* __restrict__ Qh, const ushort* __restrict__ Ql,
    const ushort* __restrict__ Kh, const ushort* __restrict__ Kl,
    const ushort* __restrict__ Vtb, const float* __restrict__ Qn,
    const float* __restrict__ Kn, const float* __restrict__ cptr,
    float* __restrict__ Opart, float* __restrict__ Npart)
{
  __shared__ ushort Es[4][16][136];    // [wave][q-row][n] (wave-private)

  const int bl = blockIdx.x;           // 0..143
  const int b  = (bl & 7) * 18 + (bl >> 3);   // bijective: pairs -> same XCD
  const int chunk = b >> 1;
  const int z = b & 1;
  const int h = blockIdx.y;
  int m = 0, base = 0;
  while (base + (m / 2 + 1) <= chunk) { base += m / 2 + 1; ++m; }
  const int n0 = 2 * (chunk - base);
  const int n1 = (n0 + 1 < m) ? (n0 + 1) : m;

  const int w = threadIdx.x >> 6;
  const int lane = threadIdx.x & 63;
  const int g = lane >> 4, lx = lane & 15;
  const int qsub = z * 4 + w;          // 0..7 (16-row q slice)
  const int qloc = qsub * 16 + lx;     // this lane's q col (0..127)

  const float cc = fmaxf(fabsf(cptr[0]), 1e-6f);
  const float is = rsqrtf(cc);
  const bool is_one = (cc == 1.0f);
  const float two_cc = 2.f * cc;

  // Q fragments (B operand) + q norm for this lane's column
  v8s bQh[2], bQl[2];
  {
    const size_t qo = (size_t)(m * 128 + qloc) * D_MODEL + h * 64 + g * 8;
    bQh[0] = *reinterpret_cast<const v8s*>(&Qh[qo]);
    bQh[1] = *reinterpret_cast<const v8s*>(&Qh[qo + 32]);
    bQl[0] = *reinterpret_cast<const v8s*>(&Ql[qo]);
    bQl[1] = *reinterpret_cast<const v8s*>(&Ql[qo + 32]);
  }
  const float qn = Qn[h * NSEQ + m * 128 + qloc];
  const float qa = fmaf(-cc, qn, 1.f);

  v4f o_acc[4];
#pragma unroll
  for (int td = 0; td < 4; ++td) o_acc[td] = v4f{0.f, 0.f, 0.f, 0.f};
  float nrm = 0.f;

  for (int n = n0; n <= n1; ++n) {
    const size_t kb = (size_t)(n * 128) * D_MODEL + h * 64;

    // ---- S^T = K.Q^T via 3-term hi/lo MFMA, K straight from L2 ----
    v4f acc[8];
#pragma unroll
    for (int tn = 0; tn < 8; ++tn) {
      const size_t ko = kb + (size_t)(tn * 16 + lx) * D_MODEL + g * 8;
      v8s ah0 = *reinterpret_cast<const v8s*>(&Kh[ko]);
      v8s ah1 = *reinterpret_cast<const v8s*>(&Kh[ko + 32]);
      v8s al0 = *reinterpret_cast<const v8s*>(&Kl[ko]);
      v8s al1 = *reinterpret_cast<const v8s*>(&Kl[ko + 32]);
      v4f a = v4f{0.f, 0.f, 0.f, 0.f};
      a = mfma16(ah0, bQh[0], a);
      a = mfma16(ah1, bQh[1], a);
      a = mfma16(ah0, bQl[0], a);
      a = mfma16(ah1, bQl[1], a);
      a = mfma16(al0, bQh[0], a);
      a = mfma16(al1, bQh[1], a);
      acc[tn] = a;
    }

    // ---- scores -> u = arg + sqrt(arg^2-1) ----
    const bool diag = (n == m);
#pragma unroll
    for (int tn = 0; tn < 8; ++tn) {
      const float4 kn4 = *reinterpret_cast<const float4*>(
          &Kn[h * NSEQ + n * 128 + tn * 16 + g * 4]);
      const float knv[4] = {kn4.x, kn4.y, kn4.z, kn4.w};
#pragma unroll
      for (int r = 0; r < 4; ++r) {
        const int krow = tn * 16 + g * 4 + r;
        const float ka = fmaf(-cc, knv[r], 1.f);
        float dsq = fmaxf(fmaf(-2.f, acc[tn][r], qn + knv[r]), 0.f);
        float den = fmaxf(qa * ka, EPSF);
        float t = fmaxf(two_cc * dsq * __builtin_amdgcn_rcpf(den), EPSF);
        float u = 1.f + t + __builtin_amdgcn_sqrtf(t * (t + 2.f));
        if (diag && krow > qloc) u = __builtin_inff();
        acc[tn][r] = u;
      }
    }

    if (is_one) {
      // e = u_min / u   (exact exp(-(acosh-acosh_min)) for c=1)
      float um = __builtin_inff();
#pragma unroll
      for (int tn = 0; tn < 8; ++tn)
#pragma unroll
        for (int r = 0; r < 4; ++r) um = fminf(um, acc[tn][r]);
      um = fminf(um, __shfl_xor(um, 16, 64));
      um = fminf(um, __shfl_xor(um, 32, 64));
#pragma unroll
      for (int tn = 0; tn < 8; ++tn) {
        float e0 = um * __builtin_amdgcn_rcpf(acc[tn][0]);
        float e1 = um * __builtin_amdgcn_rcpf(acc[tn][1]);
        float e2 = um * __builtin_amdgcn_rcpf(acc[tn][2]);
        float e3 = um * __builtin_amdgcn_rcpf(acc[tn][3]);
        nrm += (e0 + e1) + (e2 + e3);
        ushort4 ep;
        ep.x = bf16rne(e0); ep.y = bf16rne(e1); ep.z = bf16rne(e2); ep.w = bf16rne(e3);
        *reinterpret_cast<ushort4*>(&Es[w][lx][tn * 16 + g * 4]) = ep;
      }
    } else {
      float sm = -__builtin_inff();
#pragma unroll
      for (int tn = 0; tn < 8; ++tn)
#pragma unroll
        for (int r = 0; r < 4; ++r) {
          float s = -__logf(acc[tn][r]) * is;    // u=inf -> -inf
          acc[tn][r] = s;
          sm = fmaxf(sm, s);
        }
      sm = fmaxf(sm, __shfl_xor(sm, 16, 64));
      sm = fmaxf(sm, __shfl_xor(sm, 32, 64));
#pragma unroll
      for (int tn = 0; tn < 8; ++tn) {
        float e0 = __expf(acc[tn][0] - sm);
        float e1 = __expf(acc[tn][1] - sm);
        float e2 = __expf(acc[tn][2] - sm);
        float e3 = __expf(acc[tn][3] - sm);
        nrm += (e0 + e1) + (e2 + e3);
        ushort4 ep;
        ep.x = bf16rne(e0); ep.y = bf16rne(e1); ep.z = bf16rne(e2); ep.w = bf16rne(e3);
        *reinterpret_cast<ushort4*>(&Es[w][lx][tn * 16 + g * 4]) = ep;
      }
    }

    // ---- o += E @ V (wave-private E from LDS, V from L2) ----
    const ushort* Vg = Vtb + (size_t)(h * 64) * NSEQ + n * 128;
#pragma unroll
    for (int ks = 0; ks < 4; ++ks) {
      v8s ea = *reinterpret_cast<const v8s*>(&Es[w][lx][ks * 32 + g * 8]);
#pragma unroll
      for (int td = 0; td < 4; ++td) {
        v8s vb = *reinterpret_cast<const v8s*>(
            &Vg[(size_t)(td * 16 + lx) * NSEQ + ks * 32 + g * 8]);
        o_acc[td] = mfma16(ea, vb, o_acc[td]);
      }
    }
  }

  // ---- finalize: norm reduce over g, store partials ----
  nrm += __shfl_xor(nrm, 16, 64);
  nrm += __shfl_xor(nrm, 32, 64);

  float* Op = Opart + ((size_t)h * NCHUNK + chunk) * 8192;
#pragma unroll
  for (int td = 0; td < 4; ++td)
#pragma unroll
    for (int r = 0; r < 4; ++r)
      Op[(size_t)(qsub * 16 + g * 4 + r) * 64 + td * 16 + lx] = o_acc[td][r];
  if (lane < 16)
    Npart[((size_t)h * NCHUNK + chunk) * 128 + qsub * 16 + lane] = nrm;
}

// ---------------------------------------------------------------------------
// Sum partials over chunks, normalize -> Ohb (bf16). grid (64, 8), 32 rows/WG.
__global__ __launch_bounds__(256) void reduce_o(const float* __restrict__ Opart,
                                                const float* __restrict__ Npart,
                                                ushort* __restrict__ Ohb) {
  const int mq = blockIdx.x;
  const int mm = mq >> 2;
  const int rq = (mq & 3) * 32;
  const int h  = blockIdx.y;
  const int tid = threadIdx.x;
  int base = 0;
  for (int k = 0; k < mm; ++k) base += k / 2 + 1;
  const int nch = mm / 2 + 1;

  __shared__ float innorm[32];
  if (tid < 32) {
    float s = 0.f;
    for (int cI = 0; cI < nch; ++cI)
      s += Npart[((size_t)h * NCHUNK + base + cI) * 128 + rq + tid];
    innorm[tid] = 1.f / fmaxf(s, EPSF);
  }
  __syncthreads();
#pragma unroll
  for (int l = 0; l < 2; ++l) {
    int f = tid + l * 256;            // 32 rows x 16 float4
    int r = f >> 4, c4 = f & 15;
    float4 s = {0.f, 0.f, 0.f, 0.f};
    for (int cI = 0; cI < nch; ++cI) {
      const float4 p = *reinterpret_cast<const float4*>(
          &Opart[((size_t)h * NCHUNK + base + cI) * 8192 + (size_t)(rq + r) * 64 + c4 * 4]);
      s.x += p.x; s.y += p.y; s.z += p.z; s.w += p.w;
    }
    float inv = innorm[r];
    ushort4 o4;
    o4.x = bf16rne(s.x * inv); o4.y = bf16rne(s.y * inv);
    o4.z = bf16rne(s.z * inv); o4.w = bf16rne(s.w * inv);
    *reinterpret_cast<ushort4*>(
        &Ohb[(size_t)(mm * 128 + rq + r) * D_MODEL + h * 64 + c4 * 4]) = o4;
  }
}

// ---------------------------------------------------------------------------
// out = Ohb @ Wo^T + bo, 1-term bf16
__global__ __launch_bounds__(256) void o_gemm(const ushort* __restrict__ Ohb,
                                              const ushort* __restrict__ Wth,
                                              const float* __restrict__ bo,
                                              float* __restrict__ out) {
  __shared__ ushort Ah[128][40], Bh[128][40];
  const ushort* Bt = Wth + (size_t)3 * WPLANE;
  const int bx = blockIdx.x, by = blockIdx.y;
  const int tid = threadIdx.x;
  const int wid = tid >> 6, lane = tid & 63;
  const int wr = wid >> 1, wc = wid & 1;
  const int g = lane >> 4, lx = lane & 15;

  v4f acc[4][4];
#pragma unroll
  for (int i = 0; i < 4; ++i)
#pragma unroll
    for (int j = 0; j < 4; ++j) acc[i][j] = v4f{0.f, 0.f, 0.f, 0.f};

  for (int k0 = 0; k0 < 16; ++k0) {
    __syncthreads();
#pragma unroll
    for (int l = 0; l < 2; ++l) {
      int f = tid + l * 256;
      int row = f >> 2, c8 = f & 3;
      *reinterpret_cast<uint4*>(&Ah[row][c8 * 8]) =
          *reinterpret_cast<const uint4*>(&Ohb[(size_t)(by * 128 + row) * D_MODEL + k0 * 32 + c8 * 8]);
      *reinterpret_cast<uint4*>(&Bh[row][c8 * 8]) =
          *reinterpret_cast<const uint4*>(&Bt[(size_t)(bx * 128 + row) * D_MODEL + k0 * 32 + c8 * 8]);
    }
    __syncthreads();
    v8s ah[4], bh[4];
#pragma unroll
    for (int i = 0; i < 4; ++i) {
      ah[i] = *reinterpret_cast<const v8s*>(&Ah[wr * 64 + i * 16 + lx][g * 8]);
      bh[i] = *reinterpret_cast<const v8s*>(&Bh[wc * 64 + i * 16 + lx][g * 8]);
    }
#pragma unroll
    for (int i = 0; i < 4; ++i)
#pragma unroll
      for (int j = 0; j < 4; ++j)
        acc[i][j] = mfma16(ah[i], bh[j], acc[i][j]);
  }
#pragma unroll
  for (int j = 0; j < 4; ++j) {
    const int col = bx * 128 + wc * 64 + j * 16 + lx;
    const float bj = bo[col];
#pragma unroll
    for (int i = 0; i < 4; ++i)
#pragma unroll
      for (int r = 0; r < 4; ++r) {
        const int row = by * 128 + wr * 64 + i * 16 + g * 4 + r;
        out[(size_t)row * D_MODEL + col] = acc[i][j][r] + bj;
      }
  }
}

// ---------------------------------------------------------------------------
extern "C" void kernel_launch(void* const* d_in, const int* in_sizes, int n_in,
                              void* d_out, int out_size, void* d_ws, size_t ws_size,
                              hipStream_t stream) {
  (void)in_sizes; (void)n_in; (void)out_size; (void)ws_size;
  const float* x  = (const float*)d_in[0];
  const float* cfg= (const float*)d_in[1];
  const float* Wq = (const float*)d_in[2];
  const float* bq = (const float*)d_in[3];
  const float* Wk = (const float*)d_in[4];
  const float* bk = (const float*)d_in[5];
  const float* Wv = (const float*)d_in[6];
  const float* bv = (const float*)d_in[7];
  const float* Wo = (const float*)d_in[8];
  const float* bo = (const float*)d_in[9];
  float* out = (float*)d_out;

  char* p = (char*)d_ws;
  const size_t PL = (size_t)NSEQ * D_MODEL * sizeof(ushort);   // 2 MiB
  ushort* Wth = (ushort*)p;            p += 4 * (size_t)WPLANE * sizeof(ushort);
  ushort* Wtl = (ushort*)p;            p += 2 * (size_t)WPLANE * sizeof(ushort);
  ushort* Qh  = (ushort*)p;            p += PL;
  ushort* Ql  = (ushort*)p;            p += PL;
  ushort* Kh  = (ushort*)p;            p += PL;
  ushort* Kl  = (ushort*)p;            p += PL;
  ushort* Vb  = (ushort*)p;            p += PL;
  ushort* Vtb = (ushort*)p;            p += PL;
  ushort* Ohb = (ushort*)p;            p += PL;
  float*  Qn  = (float*)p;             p += (size_t)NHEADS * NSEQ * sizeof(float);
  float*  Kn  = (float*)p;             p += (size_t)NHEADS * NSEQ * sizeof(float);
  float*  Opart = (float*)p;           p += (size_t)NHEADS * NCHUNK * 8192 * sizeof(float);
  float*  Npart = (float*)p;

  prep_w<<<dim3(8, 8, 4), 256, 0, stream>>>(Wq, Wk, Wv, Wo, Wth, Wtl);
  qkv_gemm<<<dim3(4, 16, 3), 256, 0, stream>>>(x, Wth, Wtl, bq, bk, bv,
                                               Qh, Ql, Kh, Kl, Vb, Qn, Kn);
  vt_prep<<<dim3(32, 8), 256, 0, stream>>>(Vb, Vtb);
  attn<<<dim3(144, NHEADS), 256, 0, stream>>>(Qh, Ql, Kh, Kl, Vtb, Qn, Kn, cfg,
                                              Opart, Npart);
  reduce_o<<<dim3(64, NHEADS), 256, 0, stream>>>(Opart, Npart, Ohb);
  o_gemm<<<dim3(4, 16), 256, 0, stream>>>(Ohb, Wth, bo, out);
}

// Round 6
// 110.077 us; speedup vs baseline: 1.4139x; 1.4139x over previous
//
#include <hip/hip_runtime.h>
#include <math.h>

#define D_MODEL 512
#define NHEADS  8
#define NSEQ    2048
#define NBLK    16
#define NCHUNK  72          // sum over m of (m/2+1)
#define EPSF    1e-6f
#define WPLANE  262144      // 512*512 elements per weight plane

typedef _Float16 v8h __attribute__((ext_vector_type(8)));
typedef _Float16 v4h __attribute__((ext_vector_type(4)));
typedef float    v4f __attribute__((ext_vector_type(4)));

static __device__ __forceinline__ v4f mfma16h(v8h a, v8h b, v4f c) {
  return __builtin_amdgcn_mfma_f32_16x16x32_f16(a, b, c, 0, 0, 0);
}

// ---------------------------------------------------------------------------
// W[k][n] fp32 -> Wt[n][k] fp16 (4 matrices)
__global__ __launch_bounds__(256) void prep_w(const float* __restrict__ W0,
                                              const float* __restrict__ W1,
                                              const float* __restrict__ W2,
                                              const float* __restrict__ W3,
                                              _Float16* __restrict__ Wth) {
  __shared__ float T[64][68];
  const int z = blockIdx.z;
  const float* W = (z == 0) ? W0 : (z == 1) ? W1 : (z == 2) ? W2 : W3;
  const int kb = blockIdx.x * 64;
  const int nb = blockIdx.y * 64;
  const int tid = threadIdx.x;
#pragma unroll
  for (int l = 0; l < 4; ++l) {
    int f = tid + l * 256;           // 64 rows(k) x 16 float4(n)
    int row = f >> 4, c4 = f & 15;
    float4 v = *reinterpret_cast<const float4*>(&W[(size_t)(kb + row) * D_MODEL + nb + c4 * 4]);
    T[c4 * 4 + 0][row] = v.x; T[c4 * 4 + 1][row] = v.y;
    T[c4 * 4 + 2][row] = v.z; T[c4 * 4 + 3][row] = v.w;
  }
  __syncthreads();
  _Float16* oh = Wth + (size_t)z * WPLANE;
#pragma unroll
  for (int l = 0; l < 4; ++l) {
    int f = tid + l * 256;           // 64 rows(n) x 16 groups of 4(k)
    int n_ = f >> 4, k4 = f & 15;
    v4h h4;
    h4[0] = (_Float16)T[n_][k4 * 4 + 0];
    h4[1] = (_Float16)T[n_][k4 * 4 + 1];
    h4[2] = (_Float16)T[n_][k4 * 4 + 2];
    h4[3] = (_Float16)T[n_][k4 * 4 + 3];
    *reinterpret_cast<v4h*>(&oh[(size_t)(nb + n_) * D_MODEL + kb + k4 * 4]) = h4;
  }
}

// ---------------------------------------------------------------------------
// Q/K/V projections, 1-term fp16 MFMA. Norms computed from the ROUNDED
// fp16 outputs (consistency makes the acosh singularity cancel).
__global__ __launch_bounds__(256) void qkv_gemm(
    const float* __restrict__ x, const _Float16* __restrict__ Wth,
    const float* __restrict__ bq, const float* __restrict__ bk,
    const float* __restrict__ bv,
    _Float16* __restrict__ Qp, _Float16* __restrict__ Kp,
    _Float16* __restrict__ Vp,
    float* __restrict__ Qn_, float* __restrict__ Kn_) {
  __shared__ _Float16 Ah[128][40], Bh[128][40];
  const int z = blockIdx.z;
  const _Float16* Bt = Wth + (size_t)z * WPLANE;
  const float* bias = (z == 0) ? bq : (z == 1) ? bk : bv;
  _Float16* outp = (z == 0) ? Qp : (z == 1) ? Kp : Vp;

  const int bx = blockIdx.x, by = blockIdx.y;
  const int tid = threadIdx.x;
  const int wid = tid >> 6, lane = tid & 63;
  const int wr = wid >> 1, wc = wid & 1;
  const int g = lane >> 4, lx = lane & 15;

  v4f acc[4][4];
#pragma unroll
  for (int i = 0; i < 4; ++i)
#pragma unroll
    for (int j = 0; j < 4; ++j) acc[i][j] = v4f{0.f, 0.f, 0.f, 0.f};

  for (int k0 = 0; k0 < 16; ++k0) {
    __syncthreads();
#pragma unroll
    for (int l = 0; l < 4; ++l) {
      int f = tid + l * 256;          // 128 rows x 8 float4 (32 k)
      int row = f >> 3, c4 = f & 7;
      float4 a = *reinterpret_cast<const float4*>(&x[(size_t)(by * 128 + row) * D_MODEL + k0 * 32 + c4 * 4]);
      Ah[row][c4 * 4 + 0] = (_Float16)a.x;
      Ah[row][c4 * 4 + 1] = (_Float16)a.y;
      Ah[row][c4 * 4 + 2] = (_Float16)a.z;
      Ah[row][c4 * 4 + 3] = (_Float16)a.w;
    }
#pragma unroll
    for (int l = 0; l < 2; ++l) {
      int f = tid + l * 256;          // 128 rows x 4 chunks of 8
      int row = f >> 2, c8 = f & 3;
      *reinterpret_cast<uint4*>(&Bh[row][c8 * 8]) =
          *reinterpret_cast<const uint4*>(&Bt[(size_t)(bx * 128 + row) * D_MODEL + k0 * 32 + c8 * 8]);
    }
    __syncthreads();
    v8h ah[4], bh[4];
#pragma unroll
    for (int i = 0; i < 4; ++i) {
      ah[i] = *reinterpret_cast<const v8h*>(&Ah[wr * 64 + i * 16 + lx][g * 8]);
      bh[i] = *reinterpret_cast<const v8h*>(&Bh[wc * 64 + i * 16 + lx][g * 8]);
    }
#pragma unroll
    for (int i = 0; i < 4; ++i)
#pragma unroll
      for (int j = 0; j < 4; ++j)
        acc[i][j] = mfma16h(ah[i], bh[j], acc[i][j]);
  }

  float np[4][4];
#pragma unroll
  for (int i = 0; i < 4; ++i)
#pragma unroll
    for (int r = 0; r < 4; ++r) np[i][r] = 0.f;

#pragma unroll
  for (int j = 0; j < 4; ++j) {
    const int col = bx * 128 + wc * 64 + j * 16 + lx;
    const float bj = bias[col];
#pragma unroll
    for (int i = 0; i < 4; ++i)
#pragma unroll
      for (int r = 0; r < 4; ++r) {
        const int row = by * 128 + wr * 64 + i * 16 + g * 4 + r;
        float v = acc[i][j][r] + bj;
        _Float16 hv = (_Float16)v;
        outp[(size_t)row * D_MODEL + col] = hv;
        float vr = (float)hv;                 // rounded value for the norm
        np[i][r] = fmaf(vr, vr, np[i][r]);
      }
  }
  if (z < 2) {
    float* Nout = (z == 0) ? Qn_ : Kn_;
    const int hh = bx * 2 + wc;               // head of this wave's 64 cols
#pragma unroll
    for (int i = 0; i < 4; ++i)
#pragma unroll
      for (int r = 0; r < 4; ++r) {
        float s = np[i][r];
        s += __shfl_xor(s, 1, 64);
        s += __shfl_xor(s, 2, 64);
        s += __shfl_xor(s, 4, 64);
        s += __shfl_xor(s, 8, 64);
        if (lx == 0)
          Nout[hh * NSEQ + by * 128 + wr * 64 + i * 16 + g * 4 + r] = s;
      }
  }
}

// ---------------------------------------------------------------------------
// Vp [n][512] fp16 -> Vtb [h][64][2048] (d-major per head); pure bit movement.
__global__ __launch_bounds__(256) void vt_prep(const ushort* __restrict__ Vb,
                                               ushort* __restrict__ Vtb) {
  __shared__ ushort T[64][72];
  const int nb = blockIdx.x * 64;
  const int h  = blockIdx.y;
  const int tid = threadIdx.x;
#pragma unroll
  for (int l = 0; l < 2; ++l) {
    int f = tid + l * 256;            // 64 rows(n) x 8 chunks of 8(d)
    int row = f >> 3, c8 = f & 7;
    uint4 w = *reinterpret_cast<const uint4*>(&Vb[(size_t)(nb + row) * D_MODEL + h * 64 + c8 * 8]);
    const ushort* p = reinterpret_cast<const ushort*>(&w);
#pragma unroll
    for (int j = 0; j < 8; ++j) T[c8 * 8 + j][row] = p[j];
  }
  __syncthreads();
#pragma unroll
  for (int l = 0; l < 2; ++l) {
    int f = tid + l * 256;            // 64 rows(d) x 8 chunks of 8(n)
    int d = f >> 3, n8 = f & 7;
    *reinterpret_cast<uint4*>(&Vtb[(size_t)(h * 64 + d) * NSEQ + nb + n8 * 8]) =
        *reinterpret_cast<const uint4*>(&T[d][n8 * 8]);
  }
}

// ---------------------------------------------------------------------------
// Attention. grid (NCHUNK, NHEADS), 512 threads = 8 waves, 3 WG/CU.
// Wave w owns q-rows [16w,16w+16). Q frags in regs; K fp16 in LDS; V from L2.
__global__ __launch_bounds__(512, 6) void attn(
    const _Float16* __restrict__ Qp, const _Float16* __restrict__ Kp,
    const _Float16* __restrict__ Vtb, const float* __restrict__ Qn,
    const float* __restrict__ Kn, const float* __restrict__ cptr,
    float* __restrict__ Opart, float* __restrict__ Npart)
{
  __shared__ _Float16 Khs[128][68];
  __shared__ _Float16 Es[128][136];
  __shared__ float kns[128];

  const int pid2 = blockIdx.x;
  const int h    = blockIdx.y;
  int m = 0, base = 0;
  while (base + (m / 2 + 1) <= pid2) { base += m / 2 + 1; ++m; }
  const int c  = pid2 - base;
  const int n0 = 2 * c;
  const int n1 = (n0 + 1 < m) ? n0 + 1 : m;

  const int tid  = threadIdx.x;
  const int w    = tid >> 6;
  const int lane = tid & 63;
  const int g = lane >> 4, lx = lane & 15;

  const float cc = fmaxf(fabsf(cptr[0]), 1e-6f);
  const float is = rsqrtf(cc);
  const bool is_one = (cc == 1.0f);
  const float two_cc = 2.f * cc;

  // Q fragments + norms from global
  v8h aQ[2];
  {
    const size_t qoff = (size_t)(m * 128 + 16 * w + lx) * D_MODEL + h * 64 + g * 8;
    aQ[0] = *reinterpret_cast<const v8h*>(&Qp[qoff]);
    aQ[1] = *reinterpret_cast<const v8h*>(&Qp[qoff + 32]);
  }
  float qnr[4], qar[4];
#pragma unroll
  for (int r = 0; r < 4; ++r) {
    qnr[r] = Qn[h * NSEQ + m * 128 + 16 * w + g * 4 + r];
    qar[r] = fmaf(-cc, qnr[r], 1.f);
  }

  v4f o_acc[4];
#pragma unroll
  for (int td = 0; td < 4; ++td) o_acc[td] = v4f{0.f, 0.f, 0.f, 0.f};
  float nrm[4] = {0.f, 0.f, 0.f, 0.f};

  for (int n = n0; n <= n1; ++n) {
    __syncthreads();                  // prev iter's Khs readers done
    {
      const _Float16* Kg = Kp + (size_t)(n * 128) * D_MODEL + h * 64;
#pragma unroll
      for (int l = 0; l < 2; ++l) {
        int f = tid + l * 512;        // 128 rows x 8 chunks of 8
        int row = f >> 3, c8 = f & 7;
        *reinterpret_cast<uint4*>(&Khs[row][c8 * 8]) =
            *reinterpret_cast<const uint4*>(&Kg[(size_t)row * D_MODEL + c8 * 8]);
      }
      if (tid < 128) kns[tid] = Kn[h * NSEQ + n * 128 + tid];
    }
    __syncthreads();

    // ---- S = Q.K^T (1-term fp16) ----
    v4f acc[8];
#pragma unroll
    for (int tn = 0; tn < 8; ++tn) {
      v8h b0 = *reinterpret_cast<const v8h*>(&Khs[tn * 16 + lx][g * 8]);
      v8h b1 = *reinterpret_cast<const v8h*>(&Khs[tn * 16 + lx][g * 8 + 32]);
      v4f a = v4f{0.f, 0.f, 0.f, 0.f};
      a = mfma16h(aQ[0], b0, a);
      a = mfma16h(aQ[1], b1, a);
      acc[tn] = a;
    }

    // ---- u = arg + sqrt(arg^2-1), arg = 1 + t ----
    const bool diag = (n == m);
#pragma unroll
    for (int tn = 0; tn < 8; ++tn) {
      const int col = tn * 16 + lx;
      const float knc = kns[col];
      const float kac = fmaf(-cc, knc, 1.f);
#pragma unroll
      for (int r = 0; r < 4; ++r) {
        const int rowl = 16 * w + g * 4 + r;
        float dsq = fmaxf(fmaf(-2.f, acc[tn][r], qnr[r] + knc), 0.f);
        float den = fmaxf(qar[r] * kac, EPSF);
        float t = fmaxf(two_cc * dsq * __builtin_amdgcn_rcpf(den), EPSF);
        float u = 1.f + t + __builtin_amdgcn_sqrtf(t * (t + 2.f));
        if (diag && col > rowl) u = __builtin_inff();
        acc[tn][r] = u;
      }
    }

    if (is_one) {
      // e = u_min / u   (exact exp(-(acosh-acosh_min)) for c=1)
      float umin[4] = {__builtin_inff(), __builtin_inff(), __builtin_inff(), __builtin_inff()};
#pragma unroll
      for (int tn = 0; tn < 8; ++tn)
#pragma unroll
        for (int r = 0; r < 4; ++r) umin[r] = fminf(umin[r], acc[tn][r]);
#pragma unroll
      for (int d = 1; d < 16; d <<= 1)
#pragma unroll
        for (int r = 0; r < 4; ++r) umin[r] = fminf(umin[r], __shfl_xor(umin[r], d, 64));
#pragma unroll
      for (int tn = 0; tn < 8; ++tn)
#pragma unroll
        for (int r = 0; r < 4; ++r) {
          float e = umin[r] * __builtin_amdgcn_rcpf(acc[tn][r]);   // inf -> 0
          nrm[r] += e;
          Es[16 * w + g * 4 + r][tn * 16 + lx] = (_Float16)e;
        }
    } else {
      float smax[4] = {-__builtin_inff(), -__builtin_inff(), -__builtin_inff(), -__builtin_inff()};
#pragma unroll
      for (int tn = 0; tn < 8; ++tn)
#pragma unroll
        for (int r = 0; r < 4; ++r) {
          float s = -__logf(acc[tn][r]) * is;      // u=inf -> -inf
          acc[tn][r] = s;
          smax[r] = fmaxf(smax[r], s);
        }
#pragma unroll
      for (int d = 1; d < 16; d <<= 1)
#pragma unroll
        for (int r = 0; r < 4; ++r) smax[r] = fmaxf(smax[r], __shfl_xor(smax[r], d, 64));
#pragma unroll
      for (int tn = 0; tn < 8; ++tn)
#pragma unroll
        for (int r = 0; r < 4; ++r) {
          float e = __expf(acc[tn][r] - smax[r]);
          nrm[r] += e;
          Es[16 * w + g * 4 + r][tn * 16 + lx] = (_Float16)e;
        }
    }
    // Es is wave-private (rows 16w..16w+16 written and read by wave w only):
    // drain this wave's ds_writes, no block barrier needed.
    asm volatile("s_waitcnt lgkmcnt(0)" ::: "memory");
    __builtin_amdgcn_sched_barrier(0);

    // ---- o += E @ V (V frags from L2-resident Vtb) ----
    const _Float16* Vg = Vtb + (size_t)(h * 64) * NSEQ + n * 128;
#pragma unroll
    for (int ks = 0; ks < 4; ++ks) {
      v8h ea = *reinterpret_cast<const v8h*>(&Es[16 * w + lx][ks * 32 + g * 8]);
#pragma unroll
      for (int td = 0; td < 4; ++td) {
        v8h vb = *reinterpret_cast<const v8h*>(&Vg[(size_t)(td * 16 + lx) * NSEQ + ks * 32 + g * 8]);
        o_acc[td] = mfma16h(ea, vb, o_acc[td]);
      }
    }
  }

  // ---- norm reduce across tx, write partials ----
#pragma unroll
  for (int d = 1; d < 16; d <<= 1)
#pragma unroll
    for (int r = 0; r < 4; ++r) nrm[r] += __shfl_xor(nrm[r], d, 64);

  float* Op = Opart + ((size_t)h * NCHUNK + pid2) * (128 * 64);
#pragma unroll
  for (int td = 0; td < 4; ++td)
#pragma unroll
    for (int r = 0; r < 4; ++r)
      Op[(size_t)(16 * w + g * 4 + r) * 64 + td * 16 + lx] = o_acc[td][r];
  if (lx == 0) {
#pragma unroll
    for (int r = 0; r < 4; ++r)
      Npart[((size_t)h * NCHUNK + pid2) * 128 + 16 * w + g * 4 + r] = nrm[r];
  }
}

// ---------------------------------------------------------------------------
// Sum partials over chunks, normalize -> Of (fp16). grid (64, 8), 32 rows/WG.
__global__ __launch_bounds__(256) void reduce_o(const float* __restrict__ Opart,
                                                const float* __restrict__ Npart,
                                                _Float16* __restrict__ Of) {
  const int mq = blockIdx.x;
  const int mm = mq >> 2;
  const int rq = (mq & 3) * 32;
  const int h  = blockIdx.y;
  const int tid = threadIdx.x;
  int base = 0;
  for (int k = 0; k < mm; ++k) base += k / 2 + 1;
  const int nch = mm / 2 + 1;

  __shared__ float innorm[32];
  if (tid < 32) {
    float s = 0.f;
    for (int cI = 0; cI < nch; ++cI)
      s += Npart[((size_t)h * NCHUNK + base + cI) * 128 + rq + tid];
    innorm[tid] = 1.f / fmaxf(s, EPSF);
  }
  __syncthreads();
#pragma unroll
  for (int l = 0; l < 2; ++l) {
    int f = tid + l * 256;            // 32 rows x 16 float4
    int r = f >> 4, c4 = f & 15;
    float4 s = {0.f, 0.f, 0.f, 0.f};
    for (int cI = 0; cI < nch; ++cI) {
      const float4 p = *reinterpret_cast<const float4*>(
          &Opart[((size_t)h * NCHUNK + base + cI) * 8192 + (size_t)(rq + r) * 64 + c4 * 4]);
      s.x += p.x; s.y += p.y; s.z += p.z; s.w += p.w;
    }
    float inv = innorm[r];
    v4h o4;
    o4[0] = (_Float16)(s.x * inv); o4[1] = (_Float16)(s.y * inv);
    o4[2] = (_Float16)(s.z * inv); o4[3] = (_Float16)(s.w * inv);
    *reinterpret_cast<v4h*>(
        &Of[(size_t)(mm * 128 + rq + r) * D_MODEL + h * 64 + c4 * 4]) = o4;
  }
}

// ---------------------------------------------------------------------------
// out = Of @ Wo + bo, 1-term fp16
__global__ __launch_bounds__(256) void o_gemm(const _Float16* __restrict__ Of,
                                              const _Float16* __restrict__ Wth,
                                              const float* __restrict__ bo,
                                              float* __restrict__ out) {
  __shared__ _Float16 Ah[128][40], Bh[128][40];
  const _Float16* Bt = Wth + (size_t)3 * WPLANE;
  const int bx = blockIdx.x, by = blockIdx.y;
  const int tid = threadIdx.x;
  const int wid = tid >> 6, lane = tid & 63;
  const int wr = wid >> 1, wc = wid & 1;
  const int g = lane >> 4, lx = lane & 15;

  v4f acc[4][4];
#pragma unroll
  for (int i = 0; i < 4; ++i)
#pragma unroll
    for (int j = 0; j < 4; ++j) acc[i][j] = v4f{0.f, 0.f, 0.f, 0.f};

  for (int k0 = 0; k0 < 16; ++k0) {
    __syncthreads();
#pragma unroll
    for (int l = 0; l < 2; ++l) {
      int f = tid + l * 256;
      int row = f >> 2, c8 = f & 3;
      *reinterpret_cast<uint4*>(&Ah[row][c8 * 8]) =
          *reinterpret_cast<const uint4*>(&Of[(size_t)(by * 128 + row) * D_MODEL + k0 * 32 + c8 * 8]);
      *reinterpret_cast<uint4*>(&Bh[row][c8 * 8]) =
          *reinterpret_cast<const uint4*>(&Bt[(size_t)(bx * 128 + row) * D_MODEL + k0 * 32 + c8 * 8]);
    }
    __syncthreads();
    v8h ah[4], bh[4];
#pragma unroll
    for (int i = 0; i < 4; ++i) {
      ah[i] = *reinterpret_cast<const v8h*>(&Ah[wr * 64 + i * 16 + lx][g * 8]);
      bh[i] = *reinterpret_cast<const v8h*>(&Bh[wc * 64 + i * 16 + lx][g * 8]);
    }
#pragma unroll
    for (int i = 0; i < 4; ++i)
#pragma unroll
      for (int j = 0; j < 4; ++j)
        acc[i][j] = mfma16h(ah[i], bh[j], acc[i][j]);
  }
#pragma unroll
  for (int j = 0; j < 4; ++j) {
    const int col = bx * 128 + wc * 64 + j * 16 + lx;
    const float bj = bo[col];
#pragma unroll
    for (int i = 0; i < 4; ++i)
#pragma unroll
      for (int r = 0; r < 4; ++r) {
        const int row = by * 128 + wr * 64 + i * 16 + g * 4 + r;
        out[(size_t)row * D_MODEL + col] = acc[i][j][r] + bj;
      }
  }
}

// ---------------------------------------------------------------------------
extern "C" void kernel_launch(void* const* d_in, const int* in_sizes, int n_in,
                              void* d_out, int out_size, void* d_ws, size_t ws_size,
                              hipStream_t stream) {
  (void)in_sizes; (void)n_in; (void)out_size; (void)ws_size;
  const float* x  = (const float*)d_in[0];
  const float* cfg= (const float*)d_in[1];
  const float* Wq = (const float*)d_in[2];
  const float* bq = (const float*)d_in[3];
  const float* Wk = (const float*)d_in[4];
  const float* bk = (const float*)d_in[5];
  const float* Wv = (const float*)d_in[6];
  const float* bv = (const float*)d_in[7];
  const float* Wo = (const float*)d_in[8];
  const float* bo = (const float*)d_in[9];
  float* out = (float*)d_out;

  char* p = (char*)d_ws;
  const size_t PL = (size_t)NSEQ * D_MODEL * sizeof(_Float16);   // 2 MiB
  _Float16* Wth = (_Float16*)p;        p += 4 * (size_t)WPLANE * sizeof(_Float16);
  _Float16* Qp  = (_Float16*)p;        p += PL;
  _Float16* Kp  = (_Float16*)p;        p += PL;
  _Float16* Vp  = (_Float16*)p;        p += PL;
  _Float16* Vtb = (_Float16*)p;        p += PL;
  _Float16* Of  = (_Float16*)p;        p += PL;
  float*  Qn  = (float*)p;             p += (size_t)NHEADS * NSEQ * sizeof(float);
  float*  Kn  = (float*)p;             p += (size_t)NHEADS * NSEQ * sizeof(float);
  float*  Opart = (float*)p;           p += (size_t)NHEADS * NCHUNK * 8192 * sizeof(float);
  float*  Npart = (float*)p;

  prep_w<<<dim3(8, 8, 4), 256, 0, stream>>>(Wq, Wk, Wv, Wo, Wth);
  qkv_gemm<<<dim3(4, 16, 3), 256, 0, stream>>>(x, Wth, bq, bk, bv,
                                               Qp, Kp, Vp, Qn, Kn);
  vt_prep<<<dim3(32, 8), 256, 0, stream>>>((const ushort*)Vp, (ushort*)Vtb);
  attn<<<dim3(NCHUNK, NHEADS), 512, 0, stream>>>(Qp, Kp, Vtb, Qn, Kn, cfg,
                                                 Opart, Npart);
  reduce_o<<<dim3(64, NHEADS), 256, 0, stream>>>(Opart, Npart, Of);
  o_gemm<<<dim3(4, 16), 256, 0, stream>>>(Of, Wth, bo, out);
}

// Round 7
// 86.665 us; speedup vs baseline: 1.7959x; 1.2701x over previous
//
#include <hip/hip_runtime.h>
#include <math.h>

#define D_MODEL 512
#define NHEADS  8
#define NSEQ    2048
#define NBLK    16
#define NCHUNK  72          // sum over m of (m/2+1)
#define EPSF    1e-6f
#define WPLANE  262144      // 512*512 elements per weight plane

typedef _Float16 v8h __attribute__((ext_vector_type(8)));
typedef _Float16 v4h __attribute__((ext_vector_type(4)));
typedef float    v4f __attribute__((ext_vector_type(4)));

static __device__ __forceinline__ v4f mfma16h(v8h a, v8h b, v4f c) {
  return __builtin_amdgcn_mfma_f32_16x16x32_f16(a, b, c, 0, 0, 0);
}

// ---------------------------------------------------------------------------
// W[k][n] fp32 -> Wt[n][k] fp16 (4 matrices)
__global__ __launch_bounds__(256) void prep_w(const float* __restrict__ W0,
                                              const float* __restrict__ W1,
                                              const float* __restrict__ W2,
                                              const float* __restrict__ W3,
                                              _Float16* __restrict__ Wth) {
  __shared__ float T[64][68];
  const int z = blockIdx.z;
  const float* W = (z == 0) ? W0 : (z == 1) ? W1 : (z == 2) ? W2 : W3;
  const int kb = blockIdx.x * 64;
  const int nb = blockIdx.y * 64;
  const int tid = threadIdx.x;
#pragma unroll
  for (int l = 0; l < 4; ++l) {
    int f = tid + l * 256;           // 64 rows(k) x 16 float4(n)
    int row = f >> 4, c4 = f & 15;
    float4 v = *reinterpret_cast<const float4*>(&W[(size_t)(kb + row) * D_MODEL + nb + c4 * 4]);
    T[c4 * 4 + 0][row] = v.x; T[c4 * 4 + 1][row] = v.y;
    T[c4 * 4 + 2][row] = v.z; T[c4 * 4 + 3][row] = v.w;
  }
  __syncthreads();
  _Float16* oh = Wth + (size_t)z * WPLANE;
#pragma unroll
  for (int l = 0; l < 4; ++l) {
    int f = tid + l * 256;           // 64 rows(n) x 16 groups of 4(k)
    int n_ = f >> 4, k4 = f & 15;
    v4h h4;
    h4[0] = (_Float16)T[n_][k4 * 4 + 0];
    h4[1] = (_Float16)T[n_][k4 * 4 + 1];
    h4[2] = (_Float16)T[n_][k4 * 4 + 2];
    h4[3] = (_Float16)T[n_][k4 * 4 + 3];
    *reinterpret_cast<v4h*>(&oh[(size_t)(nb + n_) * D_MODEL + kb + k4 * 4]) = h4;
  }
}

// ---------------------------------------------------------------------------
// Q/K/V projections, 1-term fp16 MFMA. Norms computed from the ROUNDED
// fp16 outputs (consistency makes the acosh singularity cancel).
__global__ __launch_bounds__(256) void qkv_gemm(
    const float* __restrict__ x, const _Float16* __restrict__ Wth,
    const float* __restrict__ bq, const float* __restrict__ bk,
    const float* __restrict__ bv,
    _Float16* __restrict__ Qp, _Float16* __restrict__ Kp,
    _Float16* __restrict__ Vp,
    float* __restrict__ Qn_, float* __restrict__ Kn_) {
  __shared__ _Float16 Ah[128][40], Bh[128][40];
  const int z = blockIdx.z;
  const _Float16* Bt = Wth + (size_t)z * WPLANE;
  const float* bias = (z == 0) ? bq : (z == 1) ? bk : bv;
  _Float16* outp = (z == 0) ? Qp : (z == 1) ? Kp : Vp;

  const int bx = blockIdx.x, by = blockIdx.y;
  const int tid = threadIdx.x;
  const int wid = tid >> 6, lane = tid & 63;
  const int wr = wid >> 1, wc = wid & 1;
  const int g = lane >> 4, lx = lane & 15;

  v4f acc[4][4];
#pragma unroll
  for (int i = 0; i < 4; ++i)
#pragma unroll
    for (int j = 0; j < 4; ++j) acc[i][j] = v4f{0.f, 0.f, 0.f, 0.f};

  for (int k0 = 0; k0 < 16; ++k0) {
    __syncthreads();
#pragma unroll
    for (int l = 0; l < 4; ++l) {
      int f = tid + l * 256;          // 128 rows x 8 float4 (32 k)
      int row = f >> 3, c4 = f & 7;
      float4 a = *reinterpret_cast<const float4*>(&x[(size_t)(by * 128 + row) * D_MODEL + k0 * 32 + c4 * 4]);
      Ah[row][c4 * 4 + 0] = (_Float16)a.x;
      Ah[row][c4 * 4 + 1] = (_Float16)a.y;
      Ah[row][c4 * 4 + 2] = (_Float16)a.z;
      Ah[row][c4 * 4 + 3] = (_Float16)a.w;
    }
#pragma unroll
    for (int l = 0; l < 2; ++l) {
      int f = tid + l * 256;          // 128 rows x 4 chunks of 8
      int row = f >> 2, c8 = f & 3;
      *reinterpret_cast<uint4*>(&Bh[row][c8 * 8]) =
          *reinterpret_cast<const uint4*>(&Bt[(size_t)(bx * 128 + row) * D_MODEL + k0 * 32 + c8 * 8]);
    }
    __syncthreads();
    v8h ah[4], bh[4];
#pragma unroll
    for (int i = 0; i < 4; ++i) {
      ah[i] = *reinterpret_cast<const v8h*>(&Ah[wr * 64 + i * 16 + lx][g * 8]);
      bh[i] = *reinterpret_cast<const v8h*>(&Bh[wc * 64 + i * 16 + lx][g * 8]);
    }
#pragma unroll
    for (int i = 0; i < 4; ++i)
#pragma unroll
      for (int j = 0; j < 4; ++j)
        acc[i][j] = mfma16h(ah[i], bh[j], acc[i][j]);
  }

  float np[4][4];
#pragma unroll
  for (int i = 0; i < 4; ++i)
#pragma unroll
    for (int r = 0; r < 4; ++r) np[i][r] = 0.f;

#pragma unroll
  for (int j = 0; j < 4; ++j) {
    const int col = bx * 128 + wc * 64 + j * 16 + lx;
    const float bj = bias[col];
#pragma unroll
    for (int i = 0; i < 4; ++i)
#pragma unroll
      for (int r = 0; r < 4; ++r) {
        const int row = by * 128 + wr * 64 + i * 16 + g * 4 + r;
        float v = acc[i][j][r] + bj;
        _Float16 hv = (_Float16)v;
        outp[(size_t)row * D_MODEL + col] = hv;
        float vr = (float)hv;                 // rounded value for the norm
        np[i][r] = fmaf(vr, vr, np[i][r]);
      }
  }
  if (z < 2) {
    float* Nout = (z == 0) ? Qn_ : Kn_;
    const int hh = bx * 2 + wc;               // head of this wave's 64 cols
#pragma unroll
    for (int i = 0; i < 4; ++i)
#pragma unroll
      for (int r = 0; r < 4; ++r) {
        float s = np[i][r];
        s += __shfl_xor(s, 1, 64);
        s += __shfl_xor(s, 2, 64);
        s += __shfl_xor(s, 4, 64);
        s += __shfl_xor(s, 8, 64);
        if (lx == 0)
          Nout[hh * NSEQ + by * 128 + wr * 64 + i * 16 + g * 4 + r] = s;
      }
  }
}

// ---------------------------------------------------------------------------
// Vp [n][512] fp16 -> Vtb [h][64][2048] (d-major per head); pure bit movement.
__global__ __launch_bounds__(256) void vt_prep(const ushort* __restrict__ Vb,
                                               ushort* __restrict__ Vtb) {
  __shared__ ushort T[64][72];
  const int nb = blockIdx.x * 64;
  const int h  = blockIdx.y;
  const int tid = threadIdx.x;
#pragma unroll
  for (int l = 0; l < 2; ++l) {
    int f = tid + l * 256;            // 64 rows(n) x 8 chunks of 8(d)
    int row = f >> 3, c8 = f & 7;
    uint4 w = *reinterpret_cast<const uint4*>(&Vb[(size_t)(nb + row) * D_MODEL + h * 64 + c8 * 8]);
    const ushort* p = reinterpret_cast<const ushort*>(&w);
#pragma unroll
    for (int j = 0; j < 8; ++j) T[c8 * 8 + j][row] = p[j];
  }
  __syncthreads();
#pragma unroll
  for (int l = 0; l < 2; ++l) {
    int f = tid + l * 256;            // 64 rows(d) x 8 chunks of 8(n)
    int d = f >> 3, n8 = f & 7;
    *reinterpret_cast<uint4*>(&Vtb[(size_t)(h * 64 + d) * NSEQ + nb + n8 * 8]) =
        *reinterpret_cast<const uint4*>(&T[d][n8 * 8]);
  }
}

// ---------------------------------------------------------------------------
// Attention. grid 576 = (chunk, head) with h = bid&7 so each XCD works one
// head (K/V slice 512 KB -> L2-resident). 512 threads = 8 waves, 2 WG/CU.
// K and V staged in LDS; next iteration's tiles prefetched into registers
// during compute (T14). Es is wave-private (lgkmcnt fence only).
__global__ __launch_bounds__(512, 4) void attn(
    const _Float16* __restrict__ Qp, const _Float16* __restrict__ Kp,
    const _Float16* __restrict__ Vtb, const float* __restrict__ Qn,
    const float* __restrict__ Kn, const float* __restrict__ cptr,
    float* __restrict__ Opart, float* __restrict__ Npart)
{
  __shared__ _Float16 Khs[128][68];
  __shared__ _Float16 Vs[64][136];
  __shared__ _Float16 Es[128][136];
  __shared__ float kns[128];

  const int bid = blockIdx.x;
  const int h    = bid & 7;
  const int pid2 = bid >> 3;          // chunk 0..71
  int m = 0, base = 0;
  while (base + (m / 2 + 1) <= pid2) { base += m / 2 + 1; ++m; }
  const int c  = pid2 - base;
  const int n0 = 2 * c;
  const int n1 = (n0 + 1 < m) ? n0 + 1 : m;

  const int tid  = threadIdx.x;
  const int w    = tid >> 6;
  const int lane = tid & 63;
  const int g = lane >> 4, lx = lane & 15;

  const float cc = fmaxf(fabsf(cptr[0]), 1e-6f);
  const float is = rsqrtf(cc);
  const bool is_one = (cc == 1.0f);
  const float two_cc = 2.f * cc;

  // staging indices
  const int krow = tid >> 3, kc8 = tid & 7;      // K: 128 rows x 8 chunks(8)
  const int vrow = tid >> 4, vc8 = tid & 15;     // V: 64 rows(d) x 16 chunks(8), 2x

  const _Float16* Kgh = Kp + h * 64;
  const _Float16* Vgh = Vtb + (size_t)(h * 64) * NSEQ;

  // ---- prologue: load n0 tiles, write LDS ----
  uint4 kpre0, kpre1, vpre0, vpre1;
  float knp = 0.f;
  {
    const _Float16* Kg = Kgh + (size_t)(n0 * 128) * D_MODEL;
    kpre0 = *reinterpret_cast<const uint4*>(&Kg[(size_t)krow * D_MODEL + kc8 * 8]);
    kpre1 = *reinterpret_cast<const uint4*>(&Kg[(size_t)(krow + 64) * D_MODEL + kc8 * 8]);
    vpre0 = *reinterpret_cast<const uint4*>(&Vgh[(size_t)vrow * NSEQ + n0 * 128 + vc8 * 8]);
    vpre1 = *reinterpret_cast<const uint4*>(&Vgh[(size_t)(vrow + 32) * NSEQ + n0 * 128 + vc8 * 8]);
    if (tid < 128) knp = Kn[h * NSEQ + n0 * 128 + tid];
  }
  *reinterpret_cast<uint4*>(&Khs[krow][kc8 * 8]) = kpre0;
  *reinterpret_cast<uint4*>(&Khs[krow + 64][kc8 * 8]) = kpre1;
  *reinterpret_cast<uint4*>(&Vs[vrow][vc8 * 8]) = vpre0;
  *reinterpret_cast<uint4*>(&Vs[vrow + 32][vc8 * 8]) = vpre1;
  if (tid < 128) kns[tid] = knp;
  __syncthreads();

  // Q fragments + norms from global
  v8h aQ[2];
  {
    const size_t qoff = (size_t)(m * 128 + 16 * w + lx) * D_MODEL + h * 64 + g * 8;
    aQ[0] = *reinterpret_cast<const v8h*>(&Qp[qoff]);
    aQ[1] = *reinterpret_cast<const v8h*>(&Qp[qoff + 32]);
  }
  float qnr[4], qar[4];
#pragma unroll
  for (int r = 0; r < 4; ++r) {
    qnr[r] = Qn[h * NSEQ + m * 128 + 16 * w + g * 4 + r];
    qar[r] = fmaf(-cc, qnr[r], 1.f);
  }

  v4f o_acc[4];
#pragma unroll
  for (int td = 0; td < 4; ++td) o_acc[td] = v4f{0.f, 0.f, 0.f, 0.f};
  float nrm[4] = {0.f, 0.f, 0.f, 0.f};

  for (int n = n0; n <= n1; ++n) {
    const bool more = (n < n1);
    if (more) {                       // issue n+1 loads; they fly over compute
      const _Float16* Kg = Kgh + (size_t)((n + 1) * 128) * D_MODEL;
      kpre0 = *reinterpret_cast<const uint4*>(&Kg[(size_t)krow * D_MODEL + kc8 * 8]);
      kpre1 = *reinterpret_cast<const uint4*>(&Kg[(size_t)(krow + 64) * D_MODEL + kc8 * 8]);
      vpre0 = *reinterpret_cast<const uint4*>(&Vgh[(size_t)vrow * NSEQ + (n + 1) * 128 + vc8 * 8]);
      vpre1 = *reinterpret_cast<const uint4*>(&Vgh[(size_t)(vrow + 32) * NSEQ + (n + 1) * 128 + vc8 * 8]);
      if (tid < 128) knp = Kn[h * NSEQ + (n + 1) * 128 + tid];
    }

    // ---- S = Q.K^T (1-term fp16) ----
    v4f acc[8];
#pragma unroll
    for (int tn = 0; tn < 8; ++tn) {
      v8h b0 = *reinterpret_cast<const v8h*>(&Khs[tn * 16 + lx][g * 8]);
      v8h b1 = *reinterpret_cast<const v8h*>(&Khs[tn * 16 + lx][g * 8 + 32]);
      v4f a = v4f{0.f, 0.f, 0.f, 0.f};
      a = mfma16h(aQ[0], b0, a);
      a = mfma16h(aQ[1], b1, a);
      acc[tn] = a;
    }

    // ---- u = arg + sqrt(arg^2-1), arg = 1 + t ----
    const bool diag = (n == m);
#pragma unroll
    for (int tn = 0; tn < 8; ++tn) {
      const int col = tn * 16 + lx;
      const float knc = kns[col];
      const float kac = fmaf(-cc, knc, 1.f);
#pragma unroll
      for (int r = 0; r < 4; ++r) {
        const int rowl = 16 * w + g * 4 + r;
        float dsq = fmaxf(fmaf(-2.f, acc[tn][r], qnr[r] + knc), 0.f);
        float den = fmaxf(qar[r] * kac, EPSF);
        float t = fmaxf(two_cc * dsq * __builtin_amdgcn_rcpf(den), EPSF);
        float u = 1.f + t + __builtin_amdgcn_sqrtf(t * (t + 2.f));
        if (diag && col > rowl) u = __builtin_inff();
        acc[tn][r] = u;
      }
    }

    if (is_one) {
      // e = u_min / u   (exact exp(-(acosh-acosh_min)) for c=1)
      float umin[4] = {__builtin_inff(), __builtin_inff(), __builtin_inff(), __builtin_inff()};
#pragma unroll
      for (int tn = 0; tn < 8; ++tn)
#pragma unroll
        for (int r = 0; r < 4; ++r) umin[r] = fminf(umin[r], acc[tn][r]);
#pragma unroll
      for (int d = 1; d < 16; d <<= 1)
#pragma unroll
        for (int r = 0; r < 4; ++r) umin[r] = fminf(umin[r], __shfl_xor(umin[r], d, 64));
#pragma unroll
      for (int tn = 0; tn < 8; ++tn)
#pragma unroll
        for (int r = 0; r < 4; ++r) {
          float e = umin[r] * __builtin_amdgcn_rcpf(acc[tn][r]);   // inf -> 0
          nrm[r] += e;
          Es[16 * w + g * 4 + r][tn * 16 + lx] = (_Float16)e;
        }
    } else {
      float smax[4] = {-__builtin_inff(), -__builtin_inff(), -__builtin_inff(), -__builtin_inff()};
#pragma unroll
      for (int tn = 0; tn < 8; ++tn)
#pragma unroll
        for (int r = 0; r < 4; ++r) {
          float s = -__logf(acc[tn][r]) * is;      // u=inf -> -inf
          acc[tn][r] = s;
          smax[r] = fmaxf(smax[r], s);
        }
#pragma unroll
      for (int d = 1; d < 16; d <<= 1)
#pragma unroll
        for (int r = 0; r < 4; ++r) smax[r] = fmaxf(smax[r], __shfl_xor(smax[r], d, 64));
#pragma unroll
      for (int tn = 0; tn < 8; ++tn)
#pragma unroll
        for (int r = 0; r < 4; ++r) {
          float e = __expf(acc[tn][r] - smax[r]);
          nrm[r] += e;
          Es[16 * w + g * 4 + r][tn * 16 + lx] = (_Float16)e;
        }
    }
    // Es is wave-private: drain this wave's ds_writes, no block barrier.
    asm volatile("s_waitcnt lgkmcnt(0)" ::: "memory");
    __builtin_amdgcn_sched_barrier(0);

    // ---- o += E @ V (both from LDS) ----
#pragma unroll
    for (int ks = 0; ks < 4; ++ks) {
      v8h ea = *reinterpret_cast<const v8h*>(&Es[16 * w + lx][ks * 32 + g * 8]);
#pragma unroll
      for (int td = 0; td < 4; ++td) {
        v8h vb = *reinterpret_cast<const v8h*>(&Vs[td * 16 + lx][ks * 32 + g * 8]);
        o_acc[td] = mfma16h(ea, vb, o_acc[td]);
      }
    }

    if (more) {                       // swap in the prefetched tiles
      __syncthreads();                // everyone done reading Khs/Vs/kns
      *reinterpret_cast<uint4*>(&Khs[krow][kc8 * 8]) = kpre0;
      *reinterpret_cast<uint4*>(&Khs[krow + 64][kc8 * 8]) = kpre1;
      *reinterpret_cast<uint4*>(&Vs[vrow][vc8 * 8]) = vpre0;
      *reinterpret_cast<uint4*>(&Vs[vrow + 32][vc8 * 8]) = vpre1;
      if (tid < 128) kns[tid] = knp;
      __syncthreads();
    }
  }

  // ---- norm reduce across tx, write partials ----
#pragma unroll
  for (int d = 1; d < 16; d <<= 1)
#pragma unroll
    for (int r = 0; r < 4; ++r) nrm[r] += __shfl_xor(nrm[r], d, 64);

  float* Op = Opart + ((size_t)h * NCHUNK + pid2) * (128 * 64);
#pragma unroll
  for (int td = 0; td < 4; ++td)
#pragma unroll
    for (int r = 0; r < 4; ++r)
      Op[(size_t)(16 * w + g * 4 + r) * 64 + td * 16 + lx] = o_acc[td][r];
  if (lx == 0) {
#pragma unroll
    for (int r = 0; r < 4; ++r)
      Npart[((size_t)h * NCHUNK + pid2) * 128 + 16 * w + g * 4 + r] = nrm[r];
  }
}

// ---------------------------------------------------------------------------
// Sum partials over chunks, normalize -> Of (fp16). grid (64, 8), 32 rows/WG.
__global__ __launch_bounds__(256) void reduce_o(const float* __restrict__ Opart,
                                                const float* __restrict__ Npart,
                                                _Float16* __restrict__ Of) {
  const int mq = blockIdx.x;
  const int mm = mq >> 2;
  const int rq = (mq & 3) * 32;
  const int h  = blockIdx.y;
  const int tid = threadIdx.x;
  int base = 0;
  for (int k = 0; k < mm; ++k) base += k / 2 + 1;
  const int nch = mm / 2 + 1;

  __shared__ float innorm[32];
  if (tid < 32) {
    float s = 0.f;
    for (int cI = 0; cI < nch; ++cI)
      s += Npart[((size_t)h * NCHUNK + base + cI) * 128 + rq + tid];
    innorm[tid] = 1.f / fmaxf(s, EPSF);
  }
  __syncthreads();
#pragma unroll
  for (int l = 0; l < 2; ++l) {
    int f = tid + l * 256;            // 32 rows x 16 float4
    int r = f >> 4, c4 = f & 15;
    float4 s = {0.f, 0.f, 0.f, 0.f};
    for (int cI = 0; cI < nch; ++cI) {
      const float4 p = *reinterpret_cast<const float4*>(
          &Opart[((size_t)h * NCHUNK + base + cI) * 8192 + (size_t)(rq + r) * 64 + c4 * 4]);
      s.x += p.x; s.y += p.y; s.z += p.z; s.w += p.w;
    }
    float inv = innorm[r];
    v4h o4;
    o4[0] = (_Float16)(s.x * inv); o4[1] = (_Float16)(s.y * inv);
    o4[2] = (_Float16)(s.z * inv); o4[3] = (_Float16)(s.w * inv);
    *reinterpret_cast<v4h*>(
        &Of[(size_t)(mm * 128 + rq + r) * D_MODEL + h * 64 + c4 * 4]) = o4;
  }
}

// ---------------------------------------------------------------------------
// out = Of @ Wo + bo, 1-term fp16. 64x64 tiles, grid (8,32) = 256 WGs.
__global__ __launch_bounds__(256) void o_gemm(const _Float16* __restrict__ Of,
                                              const _Float16* __restrict__ Wth,
                                              const float* __restrict__ bo,
                                              float* __restrict__ out) {
  __shared__ _Float16 As[64][40], Bs[64][40];
  const _Float16* Bt = Wth + (size_t)3 * WPLANE;
  const int bx = blockIdx.x, by = blockIdx.y;
  const int tid = threadIdx.x;
  const int wid = tid >> 6, lane = tid & 63;
  const int wr = wid >> 1, wc = wid & 1;
  const int g = lane >> 4, lx = lane & 15;

  v4f acc[2][2];
#pragma unroll
  for (int i = 0; i < 2; ++i)
#pragma unroll
    for (int j = 0; j < 2; ++j) acc[i][j] = v4f{0.f, 0.f, 0.f, 0.f};

  const int srow = tid >> 2, sc8 = tid & 3;   // 64 rows x 4 chunks(8)
  for (int k0 = 0; k0 < 16; ++k0) {
    __syncthreads();
    *reinterpret_cast<uint4*>(&As[srow][sc8 * 8]) =
        *reinterpret_cast<const uint4*>(&Of[(size_t)(by * 64 + srow) * D_MODEL + k0 * 32 + sc8 * 8]);
    *reinterpret_cast<uint4*>(&Bs[srow][sc8 * 8]) =
        *reinterpret_cast<const uint4*>(&Bt[(size_t)(bx * 64 + srow) * D_MODEL + k0 * 32 + sc8 * 8]);
    __syncthreads();
    v8h ah[2][2], bh[2][2];
#pragma unroll
    for (int i = 0; i < 2; ++i) {
      ah[i][0] = *reinterpret_cast<const v8h*>(&As[wr * 32 + i * 16 + lx][g * 8]);
      bh[i][0] = *reinterpret_cast<const v8h*>(&Bs[wc * 32 + i * 16 + lx][g * 8]);
    }
#pragma unroll
    for (int i = 0; i < 2; ++i)
#pragma unroll
      for (int j = 0; j < 2; ++j)
        acc[i][j] = mfma16h(ah[i][0], bh[j][0], acc[i][j]);
  }
#pragma unroll
  for (int j = 0; j < 2; ++j) {
    const int col = bx * 64 + wc * 32 + j * 16 + lx;
    const float bj = bo[col];
#pragma unroll
    for (int i = 0; i < 2; ++i)
#pragma unroll
      for (int r = 0; r < 4; ++r) {
        const int row = by * 64 + wr * 32 + i * 16 + g * 4 + r;
        out[(size_t)row * D_MODEL + col] = acc[i][j][r] + bj;
      }
  }
}

// ---------------------------------------------------------------------------
extern "C" void kernel_launch(void* const* d_in, const int* in_sizes, int n_in,
                              void* d_out, int out_size, void* d_ws, size_t ws_size,
                              hipStream_t stream) {
  (void)in_sizes; (void)n_in; (void)out_size; (void)ws_size;
  const float* x  = (const float*)d_in[0];
  const float* cfg= (const float*)d_in[1];
  const float* Wq = (const float*)d_in[2];
  const float* bq = (const float*)d_in[3];
  const float* Wk = (const float*)d_in[4];
  const float* bk = (const float*)d_in[5];
  const float* Wv = (const float*)d_in[6];
  const float* bv = (const float*)d_in[7];
  const float* Wo = (const float*)d_in[8];
  const float* bo = (const float*)d_in[9];
  float* out = (float*)d_out;

  char* p = (char*)d_ws;
  const size_t PL = (size_t)NSEQ * D_MODEL * sizeof(_Float16);   // 2 MiB
  _Float16* Wth = (_Float16*)p;        p += 4 * (size_t)WPLANE * sizeof(_Float16);
  _Float16* Qp  = (_Float16*)p;        p += PL;
  _Float16* Kp  = (_Float16*)p;        p += PL;
  _Float16* Vp  = (_Float16*)p;        p += PL;
  _Float16* Vtb = (_Float16*)p;        p += PL;
  _Float16* Of  = (_Float16*)p;        p += PL;
  float*  Qn  = (float*)p;             p += (size_t)NHEADS * NSEQ * sizeof(float);
  float*  Kn  = (float*)p;             p += (size_t)NHEADS * NSEQ * sizeof(float);
  float*  Opart = (float*)p;           p += (size_t)NHEADS * NCHUNK * 8192 * sizeof(float);
  float*  Npart = (float*)p;

  prep_w<<<dim3(8, 8, 4), 256, 0, stream>>>(Wq, Wk, Wv, Wo, Wth);
  qkv_gemm<<<dim3(4, 16, 3), 256, 0, stream>>>(x, Wth, bq, bk, bv,
                                               Qp, Kp, Vp, Qn, Kn);
  vt_prep<<<dim3(32, 8), 256, 0, stream>>>((const ushort*)Vp, (ushort*)Vtb);
  attn<<<dim3(NCHUNK * NHEADS), 512, 0, stream>>>(Qp, Kp, Vtb, Qn, Kn, cfg,
                                                  Opart, Npart);
  reduce_o<<<dim3(64, NHEADS), 256, 0, stream>>>(Opart, Npart, Of);
  o_gemm<<<dim3(8, 32), 256, 0, stream>>>(Of, Wth, bo, out);
}